// Round 9
// baseline (94.130 us; speedup 1.0000x reference)
//
#include <hip/hip_runtime.h>
#include <math.h>

// Problem constants (DigitCapsules)
#define B_   64
#define IC   32
#define D_   288   // ICH*WID*HEI = 8*6*6
#define OC   10
#define OCH  16
#define J_   160   // OC*OCH
#define BJ   10240 // B_*J_
#define POISON 0xAAAAAAAAu   // harness re-poisons ws to 0xAA before EVERY launch

// ONE fused dispatch.
// Phase 1 (all 512 blocks = bt(16) x ic(32, minor -> W slice XCD-local)):
//   R6's known-good u_sum tile + u_dot partials; then each block release-stores
//   its OWN flag word (512 independent slots — no RMW line contention, unlike
//   the R7 single-counter version that regressed).
// Phase 2 (blocks 0..31 only): poll all 512 flags (relaxed, read-only), one
//   acquire + barrier, register-cache the US column ONCE, then 3 routing
//   iterations with poison-sentinel gather/broadcast barriers (2 one-way hops).
__global__ __launch_bounds__(320) void k_caps(const float* __restrict__ u,
                                              const float* __restrict__ Wt,
                                              float* __restrict__ US,
                                              float* __restrict__ UDp,
                                              unsigned* __restrict__ flag1,
                                              unsigned* __restrict__ npart,
                                              unsigned* __restrict__ nres,
                                              float* __restrict__ out) {
    const int bid = blockIdx.x;
    const int ic  = bid & 31;
    const int bt  = bid >> 5;           // 0..15
    const int tid = threadIdx.x;
    __shared__ float u_lds[4 * D_];     // [b_sub][d]
    __shared__ float part[640];         // dh=1 partials
    __shared__ float ud_part[OC];
    __shared__ float cij[OC * IC];      // [o][i] (phase 2)
    __shared__ float wred[5];
    __shared__ float nsh;
    if (tid < OC) ud_part[tid] = 0.f;
    for (int idx = tid; idx < 288; idx += 320) {   // stage u as float4s
        int b_sub = idx / 72;
        int f4    = idx - b_sub * 72;
        int b     = bt * 4 + b_sub;
        ((float4*)u_lds)[idx] =
            ((const float4*)(u + (size_t)(b * IC + ic) * D_))[f4];
    }
    __syncthreads();
    const int j4    = tid % 40;
    const int b_sub = (tid / 40) & 3;
    const int dh    = tid / 160;        // d-half
    const float4* wp = (const float4*)(Wt + (size_t)ic * D_ * J_)
                       + (size_t)dh * 144 * 40 + j4;
    const float*  ur = u_lds + b_sub * D_ + dh * 144;
    float ax = 0.f, ay = 0.f, az = 0.f, aw = 0.f;
    for (int d0 = 0; d0 < 144; d0 += 16) {
        float4 w[16];
        #pragma unroll
        for (int k = 0; k < 16; ++k) w[k] = wp[(d0 + k) * 40];   // 16 in flight
        #pragma unroll
        for (int k = 0; k < 16; ++k) {
            float uv = ur[d0 + k];
            ax += uv * w[k].x; ay += uv * w[k].y;
            az += uv * w[k].z; aw += uv * w[k].w;
        }
    }
    if (dh == 1) ((float4*)part)[tid - 160] = make_float4(ax, ay, az, aw);
    __syncthreads();
    if (dh == 0) {
        float4 p = ((float4*)part)[tid];
        ax += p.x; ay += p.y; az += p.z; aw += p.w;
        ((float4*)(US + (size_t)ic * BJ + (bt * 4 + b_sub) * J_))[j4] =
            make_float4(ax, ay, az, aw);
        float g = ax + ay + az + aw;    // u_dot partial: 4 j's share o = j4>>2
        g += __shfl_xor(g, 1);
        g += __shfl_xor(g, 2);
        if ((tid & 3) == 0) atomicAdd(&ud_part[j4 >> 2], g);
    }
    __syncthreads();
    if (tid < OC) UDp[bid * OC + tid] = ud_part[tid];
    __syncthreads();                    // every thread's US/UDp stores drained
    if (tid == 0)                       // own slot, plain release store (no RMW)
        __hip_atomic_store(&flag1[bid], 1u, __ATOMIC_RELEASE,
                           __HIP_MEMORY_SCOPE_AGENT);
    if (bid >= 32) return;              // workers done; CUs freed

    // ---- phase 2: routing (blocks 0..31, 10240 threads = one per (b,o,e)) ----
    for (int f = tid; f < 512; f += 320)            // read-only relaxed polls
        while (__hip_atomic_load(&flag1[f], __ATOMIC_RELAXED,
                                 __HIP_MEMORY_SCOPE_AGENT) == POISON)
            __builtin_amdgcn_s_sleep(1);
    __syncthreads();
    if (tid == 0)                                   // one acquire: inv L1/L2
        (void)__hip_atomic_load(&flag1[0], __ATOMIC_ACQUIRE,
                                __HIP_MEMORY_SCOPE_AGENT);
    __syncthreads();
    const int i  = tid & 31;            // in-capsule (shuffle width 32 minor)
    const int o  = tid >> 5;            // 0..9
    const int t  = bid * 320 + tid;     // b*160 + o*16 + e
    const int ot = (t >> 4) % OC;
    float us[IC];                       // US column cached ONCE (MLP-32)
    #pragma unroll
    for (int ii = 0; ii < IC; ++ii) us[ii] = US[(size_t)ii * BJ + t];
    float udv = 0.f;                    // ud[i][o] = Σ_bt UDp[(bt*32+i)*10+o]
    #pragma unroll
    for (int btt = 0; btt < 16; ++btt) udv += UDp[(btt * 32 + i) * OC + o];
    float bij = 0.f;
    for (int q = 0; q < 3; ++q) {
        // softmax over i (32 aligned lanes) for this o
        float m = bij;
        m = fmaxf(m, __shfl_xor(m, 16, 32));
        m = fmaxf(m, __shfl_xor(m,  8, 32));
        m = fmaxf(m, __shfl_xor(m,  4, 32));
        m = fmaxf(m, __shfl_xor(m,  2, 32));
        m = fmaxf(m, __shfl_xor(m,  1, 32));
        float e  = __expf(bij - m);
        float se = e;
        se += __shfl_xor(se, 16, 32);
        se += __shfl_xor(se,  8, 32);
        se += __shfl_xor(se,  4, 32);
        se += __shfl_xor(se,  2, 32);
        se += __shfl_xor(se,  1, 32);
        float c = e / se;
        cij[o * IC + i] = c;
        float cs = c * udv;             // Σ_i c·ud for this o (butterfly)
        cs += __shfl_xor(cs, 16, 32);
        cs += __shfl_xor(cs,  8, 32);
        cs += __shfl_xor(cs,  4, 32);
        cs += __shfl_xor(cs,  2, 32);
        cs += __shfl_xor(cs,  1, 32);
        __syncthreads();                // cij visible
        float s = 0.f;                  // s_t = Σ_i c[ot][i]·us[i] — pure VALU
        {
            const float* cp = cij + ot * IC;
            #pragma unroll
            for (int ii = 0; ii < IC; ++ii) s += cp[ii] * us[ii];
        }
        float a = fabsf(s);
        #pragma unroll
        for (int off = 32; off; off >>= 1) a += __shfl_down(a, off);
        if ((tid & 63) == 0) wred[tid >> 6] = a;
        __syncthreads();
        if (tid == 0)                   // publish block partial (value IS payload)
            __hip_atomic_store(&npart[q * 32 + bid],
                               __float_as_uint(wred[0] + wred[1] + wred[2] +
                                               wred[3] + wred[4]),
                               __ATOMIC_RELEASE, __HIP_MEMORY_SCOPE_AGENT);
        if (bid == 0 && tid < 32) {     // master gathers 32 partials (read-only)
            unsigned v;
            do {
                v = __hip_atomic_load(&npart[q * 32 + tid], __ATOMIC_RELAXED,
                                      __HIP_MEMORY_SCOPE_AGENT);
            } while (v == POISON);
            float p = __uint_as_float(v);
            p += __shfl_xor(p, 16, 32);
            p += __shfl_xor(p,  8, 32);
            p += __shfl_xor(p,  4, 32);
            p += __shfl_xor(p,  2, 32);
            p += __shfl_xor(p,  1, 32);
            if (tid == 0)
                __hip_atomic_store(&nres[q], __float_as_uint(p),
                                   __ATOMIC_RELEASE, __HIP_MEMORY_SCOPE_AGENT);
        }
        if (tid == 0) {                 // all blocks wait on the single result word
            unsigned v;
            while ((v = __hip_atomic_load(&nres[q], __ATOMIC_RELAXED,
                                          __HIP_MEMORY_SCOPE_AGENT)) == POISON)
                __builtin_amdgcn_s_sleep(1);
            nsh = __uint_as_float(v);
        }
        __syncthreads();
        const float n  = nsh;
        const float n2 = n * n;
        if (q < 2) {
            bij += udv * ((n2 / (1.f + n2)) * (cs / n));   // rank-1 b_ij update
        } else {
            out[t] = (n2 / (1.f + n2)) * (s / n);          // squash, final write
        }
        __syncthreads();                // protect cij/wred reuse next iter
    }
}

extern "C" void kernel_launch(void* const* d_in, const int* in_sizes, int n_in,
                              void* d_out, int out_size, void* d_ws, size_t ws_size,
                              hipStream_t stream) {
    (void)in_sizes; (void)n_in; (void)out_size; (void)ws_size;
    const float* u  = (const float*)d_in[0];
    const float* Wt = (const float*)d_in[1];
    float* ws = (float*)d_ws;
    float*    US    = ws;                        // 327680 floats: [ic][b*160+j]
    float*    UDp   = ws + 327680;               // 5120 floats: [block=512][o]
    unsigned* flag1 = (unsigned*)(ws + 332800);  // [512] phase-1 done flags
    unsigned* npart = (unsigned*)(ws + 333312);  // [3][32] iteration partials
    unsigned* nres  = (unsigned*)(ws + 333440);  // [3], own cache line

    // ONE dispatch. All sentinels rely on the 0xAA poison the harness writes
    // before every launch (sums of |s| are >=0, can never bit-equal 0xAAAAAAAA).
    k_caps<<<dim3(512), dim3(320), 0, stream>>>(u, Wt, US, UDp, flag1, npart,
                                                nres, (float*)d_out);
}

// Round 10
// 85.559 us; speedup vs baseline: 1.1002x; 1.1002x over previous
//
#include <hip/hip_runtime.h>
#include <math.h>

// Problem constants (DigitCapsules)
#define B_   64
#define IC   32
#define D_   288   // ICH*WID*HEI = 8*6*6
#define OC   10
#define OCH  16
#define J_   160   // OC*OCH
#define BJ   10240 // B_*J_
#define POISON 0xAAAAAAAAu   // harness re-poisons ws to 0xAA before EVERY launch

// K1: u_sum[ic][b*160+j] = sum_d u[b,ic,d] * W[ic,d,j]
// R9 finding: compiler compiles per-thread load batches to VGPR=32 -> MLP~3,
// leaving phase 1 latency-bound (~23 µs). Fix: COOPERATIVE double-buffered
// LDS staging of W — 320 threads x 3 independent coalesced float4 loads per
// chunk (MLP structural, VGPR-independent); compute reads W via ds_read_b128.
// New bound = LDS read throughput ≈ 7 µs.
// grid 256 = bt(8) x ic(32, minor -> XCD = ic%8, W slice L2-local);
// block 320 = b_sub(8) x j4(40); 12 chunks x 24 d.
__global__ __launch_bounds__(320) void k_usum(const float* __restrict__ u,
                                              const float* __restrict__ Wt,
                                              float* __restrict__ US,
                                              float* __restrict__ UDp) {
    const int ic  = blockIdx.x & 31;
    const int bt  = blockIdx.x >> 5;    // 0..7
    const int tid = threadIdx.x;
    __shared__ float  u_lds[8 * D_];    // 9216 B: [b_sub][d]
    __shared__ float4 wbuf[2][960];     // 2 x 15360 B: [dl(24)][j4(40)]
    __shared__ float  ud_part[OC];
    if (tid < OC) ud_part[tid] = 0.f;
    // stage u: 8 rows x 72 float4 = 576 float4, coalesced
    #pragma unroll
    for (int k = 0; k < 2; ++k) {
        int idx = tid + k * 320;
        if (idx < 576) {
            int b_sub = idx / 72, f4 = idx - b_sub * 72;
            int b = bt * 8 + b_sub;
            ((float4*)u_lds)[idx] =
                ((const float4*)u)[(size_t)(b * IC + ic) * (D_ / 4) + f4];
        }
    }
    const float4* wg = (const float4*)(Wt + (size_t)ic * D_ * J_); // [288][40]
    #pragma unroll
    for (int k = 0; k < 3; ++k)         // stage chunk 0 (960 float4)
        wbuf[0][tid + k * 320] = wg[tid + k * 320];
    __syncthreads();
    const int j4    = tid % 40;
    const int b_sub = tid / 40;
    float ax = 0.f, ay = 0.f, az = 0.f, aw = 0.f;
    for (int c = 0; c < 12; ++c) {
        const int cur = c & 1;
        float4 wn[3];
        if (c < 11) {                   // issue next chunk's loads FIRST
            #pragma unroll
            for (int k = 0; k < 3; ++k)
                wn[k] = wg[(c + 1) * 960 + tid + k * 320];
        }
        // compute current chunk from LDS (overlaps the staging latency)
        const float* uc = u_lds + b_sub * D_ + c * 24;
        #pragma unroll
        for (int dl = 0; dl < 24; ++dl) {
            float4 w  = wbuf[cur][dl * 40 + j4];
            float  uv = uc[dl];
            ax += uv * w.x; ay += uv * w.y; az += uv * w.z; aw += uv * w.w;
        }
        if (c < 11) {                   // buffer cur^1 last read in iter c-1
            #pragma unroll
            for (int k = 0; k < 3; ++k)
                wbuf[cur ^ 1][tid + k * 320] = wn[k];
        }
        __syncthreads();
    }
    ((float4*)(US + (size_t)ic * BJ + (bt * 8 + b_sub) * J_))[j4] =
        make_float4(ax, ay, az, aw);
    float g = ax + ay + az + aw;        // u_dot partial: 4 j's share o = j4>>2
    g += __shfl_xor(g, 1);
    g += __shfl_xor(g, 2);
    if ((tid & 3) == 0) atomicAdd(&ud_part[j4 >> 2], g);
    __syncthreads();
    if (tid < OC) UDp[blockIdx.x * OC + tid] = ud_part[tid];
}

// K2 (R8 verbatim, known-good): all 3 routing iterations + squash.
// grid 32 x 320, one t=(b,o,e)/thread; US column register-cached ONCE;
// poison-sentinel flag barriers (no init dispatch, no RMW contention).
__global__ __launch_bounds__(320) void k_route(const float* __restrict__ US,
                                               const float* __restrict__ UDp,
                                               unsigned* __restrict__ npart,
                                               unsigned* __restrict__ nres,
                                               float* __restrict__ out) {
    const int bid = blockIdx.x;
    const int tid = threadIdx.x;
    const int i   = tid & 31;           // in-capsule (shuffle width 32 minor)
    const int o   = tid >> 5;           // 0..9
    __shared__ float cij[OC * IC];      // [o][i]
    __shared__ float wred[5];
    __shared__ float nsh;
    const int t  = bid * 320 + tid;     // b*160 + o*16 + e
    const int ot = (t >> 4) % OC;
    float us[IC];                       // US column cached ONCE (MLP-32)
    #pragma unroll
    for (int ii = 0; ii < IC; ++ii) us[ii] = US[(size_t)ii * BJ + t];
    float udv = 0.f;                    // ud[i][o] = Σ_bt UDp[(bt*32+i)*10+o]
    #pragma unroll
    for (int bt = 0; bt < 8; ++bt) udv += UDp[(bt * 32 + i) * OC + o];
    float bij = 0.f;
    for (int q = 0; q < 3; ++q) {
        // softmax over i (32 aligned lanes) for this o
        float m = bij;
        m = fmaxf(m, __shfl_xor(m, 16, 32));
        m = fmaxf(m, __shfl_xor(m,  8, 32));
        m = fmaxf(m, __shfl_xor(m,  4, 32));
        m = fmaxf(m, __shfl_xor(m,  2, 32));
        m = fmaxf(m, __shfl_xor(m,  1, 32));
        float e  = __expf(bij - m);
        float se = e;
        se += __shfl_xor(se, 16, 32);
        se += __shfl_xor(se,  8, 32);
        se += __shfl_xor(se,  4, 32);
        se += __shfl_xor(se,  2, 32);
        se += __shfl_xor(se,  1, 32);
        float c = e / se;
        cij[o * IC + i] = c;
        float cs = c * udv;             // Σ_i c·ud for this o (butterfly)
        cs += __shfl_xor(cs, 16, 32);
        cs += __shfl_xor(cs,  8, 32);
        cs += __shfl_xor(cs,  4, 32);
        cs += __shfl_xor(cs,  2, 32);
        cs += __shfl_xor(cs,  1, 32);
        __syncthreads();                // cij visible
        float s = 0.f;                  // s_t = Σ_i c[ot][i]·us[i] — pure VALU
        {
            const float* cp = cij + ot * IC;
            #pragma unroll
            for (int ii = 0; ii < IC; ++ii) s += cp[ii] * us[ii];
        }
        float a = fabsf(s);
        #pragma unroll
        for (int off = 32; off; off >>= 1) a += __shfl_down(a, off);
        if ((tid & 63) == 0) wred[tid >> 6] = a;
        __syncthreads();
        if (tid == 0)                   // publish block partial (value IS payload)
            __hip_atomic_store(&npart[q * 32 + bid],
                               __float_as_uint(wred[0] + wred[1] + wred[2] +
                                               wred[3] + wred[4]),
                               __ATOMIC_RELEASE, __HIP_MEMORY_SCOPE_AGENT);
        if (bid == 0 && tid < 32) {     // master gathers 32 partials (read-only)
            unsigned v;
            do {
                v = __hip_atomic_load(&npart[q * 32 + tid], __ATOMIC_RELAXED,
                                      __HIP_MEMORY_SCOPE_AGENT);
            } while (v == POISON);
            float p = __uint_as_float(v);
            p += __shfl_xor(p, 16, 32);
            p += __shfl_xor(p,  8, 32);
            p += __shfl_xor(p,  4, 32);
            p += __shfl_xor(p,  2, 32);
            p += __shfl_xor(p,  1, 32);
            if (tid == 0)
                __hip_atomic_store(&nres[q], __float_as_uint(p),
                                   __ATOMIC_RELEASE, __HIP_MEMORY_SCOPE_AGENT);
        }
        if (tid == 0) {                 // all blocks wait on the single result word
            unsigned v;
            while ((v = __hip_atomic_load(&nres[q], __ATOMIC_RELAXED,
                                          __HIP_MEMORY_SCOPE_AGENT)) == POISON)
                __builtin_amdgcn_s_sleep(1);
            nsh = __uint_as_float(v);
        }
        __syncthreads();
        const float n  = nsh;
        const float n2 = n * n;
        if (q < 2) {
            bij += udv * ((n2 / (1.f + n2)) * (cs / n));   // rank-1 b_ij update
        } else {
            out[t] = (n2 / (1.f + n2)) * (s / n);          // squash, final write
        }
        __syncthreads();                // protect cij/wred reuse next iter
    }
}

extern "C" void kernel_launch(void* const* d_in, const int* in_sizes, int n_in,
                              void* d_out, int out_size, void* d_ws, size_t ws_size,
                              hipStream_t stream) {
    (void)in_sizes; (void)n_in; (void)out_size; (void)ws_size;
    const float* u  = (const float*)d_in[0];
    const float* Wt = (const float*)d_in[1];
    float* ws = (float*)d_ws;
    float*    US    = ws;                        // 327680 floats: [ic][b*160+j]
    float*    UDp   = ws + 327680;               // 2560 floats: [block=256][o]
    unsigned* npart = (unsigned*)(ws + 330240);  // [3][32] poison-sentinel slots
    unsigned* nres  = (unsigned*)(ws + 330368);  // [3], own cache line

    // 2 dispatches; no init (poison-sentinel barriers need none).
    k_usum<<<dim3(256), dim3(320), 0, stream>>>(u, Wt, US, UDp);
    k_route<<<dim3(32), dim3(320), 0, stream>>>(US, UDp, npart, nres,
                                                (float*)d_out);
}